// Round 8
// baseline (221.547 us; speedup 1.0000x reference)
//
#include <hip/hip_runtime.h>
#include <math.h>

#define H 2048
#define II 768
#define TT 512
#define EE 16

typedef float f32x4 __attribute__((ext_vector_type(4)));
typedef short s16x8 __attribute__((ext_vector_type(8)));
typedef unsigned short u16;
typedef u16 u16x4 __attribute__((ext_vector_type(4)));
typedef u16 u16x8 __attribute__((ext_vector_type(8)));

__device__ __forceinline__ u16 f2bf(float f) {
  unsigned int u = __float_as_uint(f);
  u += 0x7fffu + ((u >> 16) & 1u);   // round-to-nearest-even
  return (u16)(u >> 16);
}

// ---------------- router: logits, sigmoid, top2, counts ----------------
__global__ void router_kernel(const float* __restrict__ x, const float* __restrict__ gw,
                              int* __restrict__ counts, int* __restrict__ topi,
                              float* __restrict__ topw, int* __restrict__ pos) {
  int t = blockIdx.x;
  int tid = threadIdx.x;
  int wave = tid >> 6, lane = tid & 63;
  __shared__ float logits[EE];
  const float* xt = x + (size_t)t * H;
  for (int e = wave * 4; e < wave * 4 + 4; ++e) {
    const float* ge = gw + (size_t)e * H;
    float p = 0.f;
    for (int h = lane * 4; h < H; h += 64 * 4) {
      f32x4 xv = *(const f32x4*)(xt + h);
      f32x4 gv = *(const f32x4*)(ge + h);
      p += xv[0]*gv[0] + xv[1]*gv[1] + xv[2]*gv[2] + xv[3]*gv[3];
    }
    #pragma unroll
    for (int off = 32; off > 0; off >>= 1) p += __shfl_down(p, off);
    if (lane == 0) logits[e] = p;
  }
  __syncthreads();
  if (tid == 0) {
    float s[EE];
    #pragma unroll
    for (int e = 0; e < EE; ++e) s[e] = 1.f / (1.f + expf(-logits[e]));
    int i0 = 0;
    for (int e = 1; e < EE; ++e) if (s[e] > s[i0]) i0 = e;
    int i1 = -1;
    for (int e = 0; e < EE; ++e) {
      if (e == i0) continue;
      if (i1 < 0 || s[e] > s[i1]) i1 = e;
    }
    float w0 = s[i0], w1v = s[i1];
    float inv = 1.f / (w0 + w1v);
    w0 *= inv; w1v *= inv;
    topi[t*2+0] = i0; topi[t*2+1] = i1;
    topw[t*2+0] = w0; topw[t*2+1] = w1v;
    pos[t*2+0] = atomicAdd(&counts[i0], 1);
    pos[t*2+1] = atomicAdd(&counts[i1], 1);
  }
}

// ---------------- prefix sum over 16 experts ----------------
__global__ void prefix_kernel(const int* __restrict__ counts, int* __restrict__ base) {
  int s = 0;
  for (int e = 0; e < EE; ++e) { base[e] = s; s += counts[e]; }
  base[EE] = s;
}

// ---------------- gather tokens into expert-contiguous bf16 rows ----------------
__global__ void gather_kernel(const float* __restrict__ x, const int* __restrict__ topi,
                              const float* __restrict__ topw, const int* __restrict__ pos,
                              const int* __restrict__ base, u16* __restrict__ Xg,
                              int* __restrict__ tok_of, float* __restrict__ wt_of) {
  int t = blockIdx.x, slot = blockIdx.y;
  int e = topi[t*2 + slot];
  int row = base[e] + pos[t*2 + slot];
  if (threadIdx.x == 0) { tok_of[row] = t; wt_of[row] = topw[t*2 + slot]; }
  const float* xt = x + (size_t)t * H;
  u16* dst = Xg + (size_t)row * H;
  int h = threadIdx.x * 8;
  f32x4 v0 = *(const f32x4*)(xt + h);
  f32x4 v1 = *(const f32x4*)(xt + h + 4);
  u16x8 o;
  o[0]=f2bf(v0[0]); o[1]=f2bf(v0[1]); o[2]=f2bf(v0[2]); o[3]=f2bf(v0[3]);
  o[4]=f2bf(v1[0]); o[5]=f2bf(v1[1]); o[6]=f2bf(v1[2]); o[7]=f2bf(v1[3]);
  *(u16x8*)(dst + h) = o;
}

// ---------------- GEMM1: barrier-free wave-streaming, reg double-buffer ----------
// Wave = 64 tokens x 16 weight-rows of one matrix, K-chunk 1024 (split-K x2).
// No LDS, no __syncthreads: per-wave 2-step register lookahead; waves free-run so
// the CU memory queue never drains (fix for the burst-drain rhythm of R2-R7).
// grid (48 = nc12*mat2*kc2, 16 experts); fp32 partials atomicAdd'd into slab.
__global__ __launch_bounds__(256, 3) void gemm1_kernel(
    const u16* __restrict__ Xg,
    const float* __restrict__ w1, const float* __restrict__ w1s,
    const float* __restrict__ w3, const float* __restrict__ w3s,
    const int* __restrict__ counts, const int* __restrict__ base,
    float* __restrict__ slab) {
  const int bx = blockIdx.x;
  const int kc  = bx & 1;
  const int mat = (bx >> 1) & 1;
  const int nc  = bx >> 2;
  const int e = blockIdx.y;
  const int cnt = counts[e];
  if (cnt == 0) return;
  const int b0 = base[e];
  const int lane = threadIdx.x & 63;
  const int wv = threadIdx.x >> 6;
  const int n = nc * 64 + wv * 16 + (lane & 15);     // weight row (= out col)
  const int klo = (lane >> 4) << 3;
  const int k0 = kc * 1024;
  const float* wp = (mat ? w3 : w1) + ((size_t)e * II + n) * H + k0 + klo;
  const float* sp = (mat ? w3s : w1s) + ((size_t)e * II + n) * (H / 128) + kc * 8;
  float scl[8];
  #pragma unroll
  for (int j = 0; j < 8; ++j) scl[j] = sp[j];
  float* dst = slab + (size_t)mat * 1024 * II + n;

  for (int mt0 = 0; mt0 * 64 < cnt; ++mt0) {
    const u16* ap = Xg + (size_t)(b0 + mt0 * 64 + (lane & 15)) * H + k0 + klo;
    f32x4 acc[4] = {};
    s16x8 A[2][2][4];     // [buf][step][m-tile]
    f32x4 Bv[2][2][2];    // [buf][step][half]

#define G1_LD(bf, st, kk)                                                     \
    { _Pragma("unroll") for (int m = 0; m < 4; ++m)                           \
        A[bf][st][m] = *(const s16x8*)(ap + (size_t)m * 16 * H + (kk) * 32);  \
      Bv[bf][st][0] = *(const f32x4*)(wp + (kk) * 32);                        \
      Bv[bf][st][1] = *(const f32x4*)(wp + (kk) * 32 + 4); }

#define G1_CP(bf, st, kk)                                                     \
    { const float ss = scl[(kk) >> 2];                                        \
      u16x8 ob;                                                               \
      ob[0]=f2bf(Bv[bf][st][0][0]*ss); ob[1]=f2bf(Bv[bf][st][0][1]*ss);       \
      ob[2]=f2bf(Bv[bf][st][0][2]*ss); ob[3]=f2bf(Bv[bf][st][0][3]*ss);       \
      ob[4]=f2bf(Bv[bf][st][1][0]*ss); ob[5]=f2bf(Bv[bf][st][1][1]*ss);       \
      ob[6]=f2bf(Bv[bf][st][1][2]*ss); ob[7]=f2bf(Bv[bf][st][1][3]*ss);       \
      const s16x8 bfr = __builtin_bit_cast(s16x8, ob);                        \
      _Pragma("unroll") for (int m = 0; m < 4; ++m)                           \
        acc[m] = __builtin_amdgcn_mfma_f32_16x16x32_bf16(A[bf][st][m], bfr, acc[m], 0, 0, 0); }

    G1_LD(0, 0, 0) G1_LD(0, 1, 1)
    #pragma unroll
    for (int g = 0; g < 16; ++g) {
      if (g + 1 < 16) { G1_LD((g + 1) & 1, 0, 2 * g + 2) G1_LD((g + 1) & 1, 1, 2 * g + 3) }
      G1_CP(g & 1, 0, 2 * g) G1_CP(g & 1, 1, 2 * g + 1)
    }
#undef G1_LD
#undef G1_CP
    // epilogue: fp32 K-chunk partials -> slab
    #pragma unroll
    for (int m = 0; m < 4; ++m) {
      #pragma unroll
      for (int j = 0; j < 4; ++j) {
        const int row = mt0 * 64 + m * 16 + ((lane >> 4) << 2) + j;
        if (row < cnt) atomicAdd(dst + (size_t)(b0 + row) * II, acc[m][j]);
      }
    }
  }
}

// ---------------- silu combine: silu(g)*u -> Ag bf16 ----------------
__global__ void silu_kernel(const float* __restrict__ slab, u16* __restrict__ Ag) {
  const size_t i = ((size_t)blockIdx.x * 256 + threadIdx.x) * 4;
  f32x4 g = *(const f32x4*)(slab + i);
  f32x4 u = *(const f32x4*)(slab + (size_t)1024 * II + i);
  u16x4 o;
  #pragma unroll
  for (int j = 0; j < 4; ++j) {
    float a = g[j] / (1.f + expf(-g[j])) * u[j];
    o[j] = f2bf(a);
  }
  *(u16x4*)(Ag + i) = o;
}

// ---------------- GEMM2: barrier-free wave-streaming, reg double-buffer ----------
// Wave = 64 tokens x 16 out-cols, K-chunk 384 (split-K x2). grid (64, 16).
__global__ __launch_bounds__(256, 3) void gemm2_kernel(
    const u16* __restrict__ Ag,
    const float* __restrict__ w2, const float* __restrict__ w2s,
    const int* __restrict__ counts, const int* __restrict__ base,
    const int* __restrict__ tok_of, const float* __restrict__ wt_of,
    float* __restrict__ y) {
  const int bx = blockIdx.x;
  const int kc = bx & 1;
  const int nc = bx >> 1;
  const int e = blockIdx.y;
  const int cnt = counts[e];
  if (cnt == 0) return;
  const int b0 = base[e];
  const int lane = threadIdx.x & 63;
  const int wv = threadIdx.x >> 6;
  const int n = nc * 64 + wv * 16 + (lane & 15);     // out col 0..2047
  const int klo = (lane >> 4) << 3;
  const int k0 = kc * 384;
  const float* wp = w2 + ((size_t)e * H + n) * II + k0 + klo;
  const float* sp = w2s + ((size_t)e * H + n) * (II / 128) + kc * 3;
  float scl[3];
  #pragma unroll
  for (int j = 0; j < 3; ++j) scl[j] = sp[j];

  for (int mt0 = 0; mt0 * 64 < cnt; ++mt0) {
    const u16* ap = Ag + (size_t)(b0 + mt0 * 64 + (lane & 15)) * II + k0 + klo;
    f32x4 acc[4] = {};
    s16x8 A[2][2][4];
    f32x4 Bv[2][2][2];

#define G2_LD(bf, st, kk)                                                     \
    { _Pragma("unroll") for (int m = 0; m < 4; ++m)                           \
        A[bf][st][m] = *(const s16x8*)(ap + (size_t)m * 16 * II + (kk) * 32); \
      Bv[bf][st][0] = *(const f32x4*)(wp + (kk) * 32);                        \
      Bv[bf][st][1] = *(const f32x4*)(wp + (kk) * 32 + 4); }

#define G2_CP(bf, st, kk)                                                     \
    { const float ss = scl[(kk) >> 2];                                        \
      u16x8 ob;                                                               \
      ob[0]=f2bf(Bv[bf][st][0][0]*ss); ob[1]=f2bf(Bv[bf][st][0][1]*ss);       \
      ob[2]=f2bf(Bv[bf][st][0][2]*ss); ob[3]=f2bf(Bv[bf][st][0][3]*ss);       \
      ob[4]=f2bf(Bv[bf][st][1][0]*ss); ob[5]=f2bf(Bv[bf][st][1][1]*ss);       \
      ob[6]=f2bf(Bv[bf][st][1][2]*ss); ob[7]=f2bf(Bv[bf][st][1][3]*ss);       \
      const s16x8 bfr = __builtin_bit_cast(s16x8, ob);                        \
      _Pragma("unroll") for (int m = 0; m < 4; ++m)                           \
        acc[m] = __builtin_amdgcn_mfma_f32_16x16x32_bf16(A[bf][st][m], bfr, acc[m], 0, 0, 0); }

    G2_LD(0, 0, 0) G2_LD(0, 1, 1)
    #pragma unroll
    for (int g = 0; g < 6; ++g) {
      if (g + 1 < 6) { G2_LD((g + 1) & 1, 0, 2 * g + 2) G2_LD((g + 1) & 1, 1, 2 * g + 3) }
      G2_CP(g & 1, 0, 2 * g) G2_CP(g & 1, 1, 2 * g + 1)
    }
#undef G2_LD
#undef G2_CP
    // epilogue: weighted scatter-add into y
    #pragma unroll
    for (int m = 0; m < 4; ++m) {
      #pragma unroll
      for (int j = 0; j < 4; ++j) {
        const int row = mt0 * 64 + m * 16 + ((lane >> 4) << 2) + j;
        if (row < cnt) {
          const int grow = b0 + row;
          const int tk = tok_of[grow];
          const float wt = wt_of[grow];
          atomicAdd(y + (size_t)tk * H + n, acc[m][j] * wt);
        }
      }
    }
  }
}

extern "C" void kernel_launch(void* const* d_in, const int* in_sizes, int n_in,
                              void* d_out, int out_size, void* d_ws, size_t ws_size,
                              hipStream_t stream) {
  const float* x   = (const float*)d_in[0];
  const float* gw  = (const float*)d_in[1];
  const float* w1  = (const float*)d_in[2];
  const float* w1s = (const float*)d_in[3];
  const float* w3  = (const float*)d_in[4];
  const float* w3s = (const float*)d_in[5];
  const float* w2  = (const float*)d_in[6];
  const float* w2s = (const float*)d_in[7];
  float* y = (float*)d_out;

  char* ws = (char*)d_ws;
  int*   counts = (int*)(ws + 0);            // 16 ints
  int*   basep  = (int*)(ws + 64);           // 17 ints
  int*   topi   = (int*)(ws + 256);          // 1024 ints
  float* topw   = (float*)(ws + 256 + 4096);
  int*   pos    = (int*)(ws + 256 + 8192);
  int*   tok_of = (int*)(ws + 256 + 12288);
  float* wt_of  = (float*)(ws + 256 + 16384);
  u16*   Xg     = (u16*)(ws + 20736);                     // 1152 x 2048 bf16 = 4718592 B
  u16*   Ag     = (u16*)(ws + 20736 + 4718592);           // 1152 x 768 bf16  = 1769472 B
  float* slab   = (float*)(ws + 20736 + 4718592 + 1769472); // [2][1024][768] f32 = 6291456 B

  hipMemsetAsync(counts, 0, 64, stream);
  hipMemsetAsync(y, 0, (size_t)out_size * sizeof(float), stream);
  hipMemsetAsync(slab, 0, (size_t)2 * 1024 * II * sizeof(float), stream);

  router_kernel<<<TT, 256, 0, stream>>>(x, gw, counts, topi, topw, pos);
  prefix_kernel<<<1, 1, 0, stream>>>(counts, basep);
  gather_kernel<<<dim3(TT, 2), 256, 0, stream>>>(x, topi, topw, pos, basep, Xg, tok_of, wt_of);
  gemm1_kernel<<<dim3(48, EE), 256, 0, stream>>>(Xg, w1, w1s, w3, w3s, counts, basep, slab);
  silu_kernel<<<(1024 * II) / (256 * 4), 256, 0, stream>>>(slab, Ag);
  gemm2_kernel<<<dim3(64, EE), 256, 0, stream>>>(Ag, w2, w2s, counts, basep, tok_of, wt_of, y);
}

// Round 9
// 153.810 us; speedup vs baseline: 1.4404x; 1.4404x over previous
//
#include <hip/hip_runtime.h>
#include <math.h>

#define H 2048
#define II 768
#define TT 512
#define EE 16
#define BK 64

typedef float f32x4 __attribute__((ext_vector_type(4)));
typedef short s16x8 __attribute__((ext_vector_type(8)));
typedef unsigned short u16;
typedef u16 u16x4 __attribute__((ext_vector_type(4)));
typedef u16 u16x8 __attribute__((ext_vector_type(8)));

__device__ __forceinline__ u16 f2bf(float f) {
  unsigned int u = __float_as_uint(f);
  u += 0x7fffu + ((u >> 16) & 1u);   // round-to-nearest-even
  return (u16)(u >> 16);
}

// ---------------- router: logits, sigmoid, top2, counts ----------------
__global__ void router_kernel(const float* __restrict__ x, const float* __restrict__ gw,
                              int* __restrict__ counts, int* __restrict__ topi,
                              float* __restrict__ topw, int* __restrict__ pos) {
  int t = blockIdx.x;
  int tid = threadIdx.x;
  int wave = tid >> 6, lane = tid & 63;
  __shared__ float logits[EE];
  const float* xt = x + (size_t)t * H;
  for (int e = wave * 4; e < wave * 4 + 4; ++e) {
    const float* ge = gw + (size_t)e * H;
    float p = 0.f;
    for (int h = lane * 4; h < H; h += 64 * 4) {
      f32x4 xv = *(const f32x4*)(xt + h);
      f32x4 gv = *(const f32x4*)(ge + h);
      p += xv[0]*gv[0] + xv[1]*gv[1] + xv[2]*gv[2] + xv[3]*gv[3];
    }
    #pragma unroll
    for (int off = 32; off > 0; off >>= 1) p += __shfl_down(p, off);
    if (lane == 0) logits[e] = p;
  }
  __syncthreads();
  if (tid == 0) {
    float s[EE];
    #pragma unroll
    for (int e = 0; e < EE; ++e) s[e] = 1.f / (1.f + expf(-logits[e]));
    int i0 = 0;
    for (int e = 1; e < EE; ++e) if (s[e] > s[i0]) i0 = e;
    int i1 = -1;
    for (int e = 0; e < EE; ++e) {
      if (e == i0) continue;
      if (i1 < 0 || s[e] > s[i1]) i1 = e;
    }
    float w0 = s[i0], w1v = s[i1];
    float inv = 1.f / (w0 + w1v);
    w0 *= inv; w1v *= inv;
    topi[t*2+0] = i0; topi[t*2+1] = i1;
    topw[t*2+0] = w0; topw[t*2+1] = w1v;
    pos[t*2+0] = atomicAdd(&counts[i0], 1);
    pos[t*2+1] = atomicAdd(&counts[i1], 1);
  }
}

// ---------------- prefix sum over 16 experts ----------------
__global__ void prefix_kernel(const int* __restrict__ counts, int* __restrict__ base) {
  int s = 0;
  for (int e = 0; e < EE; ++e) { base[e] = s; s += counts[e]; }
  base[EE] = s;
}

// ---------------- gather tokens into expert-contiguous bf16 rows ----------------
__global__ void gather_kernel(const float* __restrict__ x, const int* __restrict__ topi,
                              const float* __restrict__ topw, const int* __restrict__ pos,
                              const int* __restrict__ base, u16* __restrict__ Xg,
                              int* __restrict__ tok_of, float* __restrict__ wt_of) {
  int t = blockIdx.x, slot = blockIdx.y;
  int e = topi[t*2 + slot];
  int row = base[e] + pos[t*2 + slot];
  if (threadIdx.x == 0) { tok_of[row] = t; wt_of[row] = topw[t*2 + slot]; }
  const float* xt = x + (size_t)t * H;
  u16* dst = Xg + (size_t)row * H;
  int h = threadIdx.x * 8;
  f32x4 v0 = *(const f32x4*)(xt + h);
  f32x4 v1 = *(const f32x4*)(xt + h + 4);
  u16x8 o;
  o[0]=f2bf(v0[0]); o[1]=f2bf(v0[1]); o[2]=f2bf(v0[2]); o[3]=f2bf(v0[3]);
  o[4]=f2bf(v1[0]); o[5]=f2bf(v1[1]); o[6]=f2bf(v1[2]); o[7]=f2bf(v1[3]);
  *(u16x8*)(dst + h) = o;
}

// ---------------- GEMM1: R7 geometry + 2-deep pipeline, counted vmcnt ----------------
// BM=128, BN=64 x {w1,w3}, BK=64, split-K x4, grid (48,16). Double-buffered LDS,
// raw s_barrier (NO vmcnt drain): tile t+2's 12 loads stay in flight across the
// barrier; compiler emits vmcnt(12) at the convert's register use (T3/T4).
__global__ __launch_bounds__(256, 2) void gemm1_kernel(
    const u16* __restrict__ Xg,
    const float* __restrict__ w1, const float* __restrict__ w1s,
    const float* __restrict__ w3, const float* __restrict__ w3s,
    const int* __restrict__ counts, const int* __restrict__ base,
    float* __restrict__ slab) {
  const int nc = blockIdx.x >> 2, kc = blockIdx.x & 3;
  const int e = blockIdx.y;
  const int cnt = counts[e];
  if (cnt == 0) return;
  const int n0 = nc * 64;
  const int k0 = kc * 512;
  const int b0 = base[e];
  const int tid = threadIdx.x;
  const int lane = tid & 63;
  const int wv = tid >> 6;
  const int wm = wv >> 1, wn = wv & 1;   // wn: 0 -> w1 (G), 1 -> w3 (U)

  __shared__ __align__(16) u16 As[2][128 * 64];     // 32 KB
  __shared__ __align__(16) u16 Bs[2][2][64 * 64];   // 32 KB  [buf][mat]

  // staging coords (identical to R7)
  const int rA  = tid >> 1;              // 0..127
  const int ch  = tid & 1;
  const int cqA = ch << 5;
  const int swzA = (rA & 7) << 3;
  const int matB = rA >> 6;
  const int rB   = rA & 63;
  const int swzB = (rB & 7) << 3;
  const float* wsrc = (matB ? w3 : w1) + ((size_t)e * II + n0 + rB) * H + k0 + ch * 32;
  const float* ssrc = (matB ? w3s : w1s) + ((size_t)e * II + n0 + rB) * (H / 128) + kc * 4;
  float scl[4];
  #pragma unroll
  for (int j = 0; j < 4; ++j) scl[j] = ssrc[j];

  // compute coords (identical to R7)
  const int rswz = (lane & 7) << 3;
  const int acol0 = (lane >> 4) << 3;

  float* dst = slab + (size_t)wn * 1024 * II;

  const int nmt = (cnt + 127) >> 7;
  for (int mt = 0; mt < nmt; ++mt) {
    const u16* asrc = Xg + (size_t)(b0 + mt * 128 + rA) * H + k0 + cqA;
    f32x4 acc[4][4] = {};
    s16x8 av[2][4];      // [tile parity][frag]
    f32x4 bv[2][8];

#define G1_ISSUE(t, P)                                                         \
    { const int kk = (t) * BK;                                                 \
      _Pragma("unroll") for (int j = 0; j < 4; ++j)                            \
        av[P][j] = *(const s16x8*)(asrc + kk + j * 8);                         \
      _Pragma("unroll") for (int j = 0; j < 8; ++j)                            \
        bv[P][j] = *(const f32x4*)(wsrc + kk + j * 4); }

#define G1_CONVW(t, P)                                                         \
    { u16* abuf = &As[(t) & 1][0];                                             \
      u16* bbuf = &Bs[(t) & 1][matB][0];                                       \
      _Pragma("unroll") for (int j = 0; j < 4; ++j)                            \
        *(s16x8*)(abuf + rA * 64 + ((cqA + j * 8) ^ swzA)) = av[P][j];         \
      const float ss = scl[(t) >> 1];                                          \
      _Pragma("unroll") for (int j = 0; j < 4; ++j) {                          \
        u16x8 ob;                                                              \
        ob[0]=f2bf(bv[P][2*j][0]*ss); ob[1]=f2bf(bv[P][2*j][1]*ss);            \
        ob[2]=f2bf(bv[P][2*j][2]*ss); ob[3]=f2bf(bv[P][2*j][3]*ss);            \
        ob[4]=f2bf(bv[P][2*j+1][0]*ss); ob[5]=f2bf(bv[P][2*j+1][1]*ss);        \
        ob[6]=f2bf(bv[P][2*j+1][2]*ss); ob[7]=f2bf(bv[P][2*j+1][3]*ss);        \
        *(u16x8*)(bbuf + rB * 64 + ((ch * 32 + j * 8) ^ swzB)) = ob; } }

#define G1_MFMA(t)                                                             \
    { const u16* abuf = &As[(t) & 1][0];                                       \
      const u16* bbuf = &Bs[(t) & 1][wn][0];                                   \
      _Pragma("unroll") for (int ks = 0; ks < 2; ++ks) {                       \
        const int ac = ks * 32 + acol0;                                        \
        s16x8 bf[4];                                                           \
        _Pragma("unroll") for (int nf = 0; nf < 4; ++nf)                       \
          bf[nf] = *(const s16x8*)(bbuf + (nf * 16 + (lane & 15)) * 64 + (ac ^ rswz)); \
        _Pragma("unroll") for (int mi = 0; mi < 4; ++mi) {                     \
          const int arow = wm * 64 + mi * 16 + (lane & 15);                    \
          s16x8 af = *(const s16x8*)(abuf + arow * 64 + (ac ^ rswz));          \
          _Pragma("unroll") for (int nf = 0; nf < 4; ++nf)                     \
            acc[mi][nf] = __builtin_amdgcn_mfma_f32_16x16x32_bf16(af, bf[nf], acc[mi][nf], 0, 0, 0); } } }

    // prologue: tiles 0 and 1 in flight; tile 0 converted to LDS buf0
    G1_ISSUE(0, 0)
    G1_ISSUE(1, 1)
    G1_CONVW(0, 0)
    asm volatile("s_waitcnt lgkmcnt(0)" ::: "memory");
    __builtin_amdgcn_s_barrier();
    #pragma unroll
    for (int t = 0; t < 8; ++t) {
      if (t + 2 < 8) { G1_ISSUE(t + 2, t & 1) }      // keeps 12 loads in flight
      G1_MFMA(t)
      if (t + 1 < 8) {
        G1_CONVW(t + 1, (t + 1) & 1)                 // compiler: vmcnt(12) here, not 0
        asm volatile("s_waitcnt lgkmcnt(0)" ::: "memory");
        __builtin_amdgcn_s_barrier();                // raw barrier: no vmcnt drain
      }
    }
#undef G1_ISSUE
#undef G1_CONVW
#undef G1_MFMA

    // epilogue: atomicAdd K-chunk partials into G/U slab (identical to R7)
    #pragma unroll
    for (int mi = 0; mi < 4; ++mi) {
      #pragma unroll
      for (int r4 = 0; r4 < 4; ++r4) {
        const int mrow = mt * 128 + wm * 64 + mi * 16 + ((lane >> 4) << 2) + r4;
        if (mrow < cnt) {
          #pragma unroll
          for (int nf = 0; nf < 4; ++nf)
            atomicAdd(dst + (size_t)(b0 + mrow) * II + n0 + nf * 16 + (lane & 15),
                      acc[mi][nf][r4]);
        }
      }
    }
    if (mt + 1 < nmt) __builtin_amdgcn_s_barrier();
  }
}

// ---------------- silu combine: silu(g)*u -> Ag bf16 ----------------
__global__ void silu_kernel(const float* __restrict__ slab, u16* __restrict__ Ag) {
  const size_t i = ((size_t)blockIdx.x * 256 + threadIdx.x) * 4;
  f32x4 g = *(const f32x4*)(slab + i);
  f32x4 u = *(const f32x4*)(slab + (size_t)1024 * II + i);
  u16x4 o;
  #pragma unroll
  for (int j = 0; j < 4; ++j) {
    float a = g[j] / (1.f + expf(-g[j])) * u[j];
    o[j] = f2bf(a);
  }
  *(u16x4*)(Ag + i) = o;
}

// ---------------- GEMM2: R7 geometry + 2-deep pipeline, counted vmcnt ----------------
// BM=128, BN=64, BK=64, split-K x2, grid (64,16). Same sync structure as gemm1.
__global__ __launch_bounds__(256, 3) void gemm2_kernel(
    const u16* __restrict__ Ag,
    const float* __restrict__ w2, const float* __restrict__ w2s,
    const int* __restrict__ counts, const int* __restrict__ base,
    const int* __restrict__ tok_of, const float* __restrict__ wt_of,
    float* __restrict__ y) {
  const int nc = blockIdx.x >> 1, kc = blockIdx.x & 1;
  const int e = blockIdx.y;
  const int cnt = counts[e];
  if (cnt == 0) return;
  const int n0 = nc * 64;
  const int k0 = kc * 384;
  const int b0 = base[e];
  const int tid = threadIdx.x;
  const int lane = tid & 63;
  const int wv = tid >> 6;
  const int wm = wv >> 1, wn = wv & 1;

  __shared__ __align__(16) u16 As[2][128 * 64];   // 32 KB
  __shared__ __align__(16) u16 Bs[2][64 * 64];    // 16 KB

  const int rA  = tid >> 1;
  const int cqA = (tid & 1) << 5;
  const int swzA = (rA & 7) << 3;
  const int rB  = tid >> 2;              // 0..63
  const int cqB = (tid & 3) << 4;        // 16 f32 per thread
  const int swzB = (rB & 7) << 3;
  const float* wsrc = w2 + ((size_t)e * H + n0 + rB) * II + k0 + cqB;
  const float* ssrc = w2s + ((size_t)e * H + n0 + rB) * (II / 128) + kc * 3;
  float scl[3];
  #pragma unroll
  for (int j = 0; j < 3; ++j) scl[j] = ssrc[j];

  const int rswz = (lane & 7) << 3;
  const int acol0 = (lane >> 4) << 3;

  const int nmt = (cnt + 127) >> 7;
  for (int mt = 0; mt < nmt; ++mt) {
    const u16* asrc = Ag + (size_t)(b0 + mt * 128 + rA) * II + k0 + cqA;
    f32x4 acc[4][2] = {};
    s16x8 av[2][4];
    f32x4 bv[2][4];

#define G2_ISSUE(t, P)                                                         \
    { const int kk = (t) * BK;                                                 \
      _Pragma("unroll") for (int j = 0; j < 4; ++j)                            \
        av[P][j] = *(const s16x8*)(asrc + kk + j * 8);                         \
      _Pragma("unroll") for (int j = 0; j < 4; ++j)                            \
        bv[P][j] = *(const f32x4*)(wsrc + kk + j * 4); }

#define G2_CONVW(t, P)                                                         \
    { u16* abuf = &As[(t) & 1][0];                                             \
      u16* bbuf = &Bs[(t) & 1][0];                                             \
      _Pragma("unroll") for (int j = 0; j < 4; ++j)                            \
        *(s16x8*)(abuf + rA * 64 + ((cqA + j * 8) ^ swzA)) = av[P][j];         \
      const float ss = scl[(t) >> 1];                                          \
      _Pragma("unroll") for (int j = 0; j < 2; ++j) {                          \
        u16x8 ob;                                                              \
        ob[0]=f2bf(bv[P][2*j][0]*ss); ob[1]=f2bf(bv[P][2*j][1]*ss);            \
        ob[2]=f2bf(bv[P][2*j][2]*ss); ob[3]=f2bf(bv[P][2*j][3]*ss);            \
        ob[4]=f2bf(bv[P][2*j+1][0]*ss); ob[5]=f2bf(bv[P][2*j+1][1]*ss);        \
        ob[6]=f2bf(bv[P][2*j+1][2]*ss); ob[7]=f2bf(bv[P][2*j+1][3]*ss);        \
        *(u16x8*)(bbuf + rB * 64 + ((cqB + j * 8) ^ swzB)) = ob; } }

#define G2_MFMA(t)                                                             \
    { const u16* abuf = &As[(t) & 1][0];                                       \
      const u16* bbuf = &Bs[(t) & 1][0];                                       \
      _Pragma("unroll") for (int ks = 0; ks < 2; ++ks) {                       \
        const int ac = ks * 32 + acol0;                                        \
        s16x8 bf[2];                                                           \
        _Pragma("unroll") for (int ni = 0; ni < 2; ++ni) {                     \
          const int brn = wn * 32 + ni * 16 + (lane & 15);                     \
          bf[ni] = *(const s16x8*)(bbuf + brn * 64 + (ac ^ rswz)); }           \
        _Pragma("unroll") for (int mi = 0; mi < 4; ++mi) {                     \
          const int arow = wm * 64 + mi * 16 + (lane & 15);                    \
          s16x8 af = *(const s16x8*)(abuf + arow * 64 + (ac ^ rswz));          \
          acc[mi][0] = __builtin_amdgcn_mfma_f32_16x16x32_bf16(af, bf[0], acc[mi][0], 0, 0, 0); \
          acc[mi][1] = __builtin_amdgcn_mfma_f32_16x16x32_bf16(af, bf[1], acc[mi][1], 0, 0, 0); } } }

    G2_ISSUE(0, 0)
    G2_ISSUE(1, 1)
    G2_CONVW(0, 0)
    asm volatile("s_waitcnt lgkmcnt(0)" ::: "memory");
    __builtin_amdgcn_s_barrier();
    #pragma unroll
    for (int t = 0; t < 6; ++t) {
      if (t + 2 < 6) { G2_ISSUE(t + 2, t & 1) }
      G2_MFMA(t)
      if (t + 1 < 6) {
        G2_CONVW(t + 1, (t + 1) & 1)
        asm volatile("s_waitcnt lgkmcnt(0)" ::: "memory");
        __builtin_amdgcn_s_barrier();
      }
    }
#undef G2_ISSUE
#undef G2_CONVW
#undef G2_MFMA

    // epilogue: weighted scatter-add into y (identical to R7)
    #pragma unroll
    for (int mi = 0; mi < 4; ++mi) {
      #pragma unroll
      for (int r4 = 0; r4 < 4; ++r4) {
        const int mrow = mt * 128 + wm * 64 + mi * 16 + ((lane >> 4) << 2) + r4;
        if (mrow < cnt) {
          const int grow = b0 + mrow;
          const int tk = tok_of[grow];
          const float wt = wt_of[grow];
          #pragma unroll
          for (int ni = 0; ni < 2; ++ni)
            atomicAdd(y + (size_t)tk * H + n0 + wn * 32 + ni * 16 + (lane & 15),
                      acc[mi][ni][r4] * wt);
        }
      }
    }
    if (mt + 1 < nmt) __builtin_amdgcn_s_barrier();
  }
}

extern "C" void kernel_launch(void* const* d_in, const int* in_sizes, int n_in,
                              void* d_out, int out_size, void* d_ws, size_t ws_size,
                              hipStream_t stream) {
  const float* x   = (const float*)d_in[0];
  const float* gw  = (const float*)d_in[1];
  const float* w1  = (const float*)d_in[2];
  const float* w1s = (const float*)d_in[3];
  const float* w3  = (const float*)d_in[4];
  const float* w3s = (const float*)d_in[5];
  const float* w2  = (const float*)d_in[6];
  const float* w2s = (const float*)d_in[7];
  float* y = (float*)d_out;

  char* ws = (char*)d_ws;
  int*   counts = (int*)(ws + 0);            // 16 ints
  int*   basep  = (int*)(ws + 64);           // 17 ints
  int*   topi   = (int*)(ws + 256);          // 1024 ints
  float* topw   = (float*)(ws + 256 + 4096);
  int*   pos    = (int*)(ws + 256 + 8192);
  int*   tok_of = (int*)(ws + 256 + 12288);
  float* wt_of  = (float*)(ws + 256 + 16384);
  u16*   Xg     = (u16*)(ws + 20736);                     // 1152 x 2048 bf16 = 4718592 B
  u16*   Ag     = (u16*)(ws + 20736 + 4718592);           // 1152 x 768 bf16  = 1769472 B
  float* slab   = (float*)(ws + 20736 + 4718592 + 1769472); // [2][1024][768] f32 = 6291456 B

  hipMemsetAsync(counts, 0, 64, stream);
  hipMemsetAsync(y, 0, (size_t)out_size * sizeof(float), stream);
  hipMemsetAsync(slab, 0, (size_t)2 * 1024 * II * sizeof(float), stream);

  router_kernel<<<TT, 256, 0, stream>>>(x, gw, counts, topi, topw, pos);
  prefix_kernel<<<1, 1, 0, stream>>>(counts, basep);
  gather_kernel<<<dim3(TT, 2), 256, 0, stream>>>(x, topi, topw, pos, basep, Xg, tok_of, wt_of);
  gemm1_kernel<<<dim3(48, EE), 256, 0, stream>>>(Xg, w1, w1s, w3, w3s, counts, basep, slab);
  silu_kernel<<<(1024 * II) / (256 * 4), 256, 0, stream>>>(slab, Ag);
  gemm2_kernel<<<dim3(64, EE), 256, 0, stream>>>(Ag, w2, w2s, counts, basep, tok_of, wt_of, y);
}